// Round 3
// baseline (165.641 us; speedup 1.0000x reference)
//
#include <hip/hip_runtime.h>

#define BC 4096      // rows of hidden_current
#define BP 8192      // rows of hidden_previous
#define D  768
#define KNB 5
#define TOPK 6
#define NT (BP / 128)   // 64 column tiles (128 cols each) of the similarity matrix
#define NKT (D / 64)    // 12 K-tiles of 64
#define NIT (NKT / 2)   // 6 iterations, 2 K-tiles each

typedef __bf16 bf16x8 __attribute__((ext_vector_type(8)));
typedef float  f32x4  __attribute__((ext_vector_type(4)));

__device__ __forceinline__ unsigned short f2bf(float f) {
    unsigned int u = __float_as_uint(f);
    u += 0x7fffu + ((u >> 16) & 1u);          // round-to-nearest-even
    return (unsigned short)(u >> 16);
}

__device__ __forceinline__ void gload16(const void* g, void* l) {
    __builtin_amdgcn_global_load_lds(
        (const __attribute__((address_space(1))) unsigned int*)g,
        (__attribute__((address_space(3))) unsigned int*)l, 16, 0, 0);
}

// Float+int insertion network — used by k_mergeloss (global merge, exact indices).
__device__ __forceinline__ void topk_insert(float v, int j, float* bv, int* bj) {
    #pragma unroll
    for (int q = TOPK - 1; q >= 1; q--) {
        bool up   = v > bv[q - 1];
        bool here = (v > bv[q]) && !up;
        bv[q] = up ? bv[q - 1] : (here ? v : bv[q]);
        bj[q] = up ? bj[q - 1] : (here ? j : bj[q]);
    }
    if (v > bv[0]) { bv[0] = v; bj[0] = j; }
}

// Packed-key bubble insert (r17): bk[] sorted DESCENDING; one pass of pure
// v_max_u32/v_min_u32 (12 VOP2 ops, no cndmask). Keys unique (packed col bits).
__device__ __forceinline__ void topk_insert_u(unsigned v, unsigned* bk) {
    unsigned c = v;
    #pragma unroll
    for (int q = 0; q < TOPK; q++) {
        unsigned hi = (c > bk[q]) ? c : bk[q];   // v_max_u32
        c           = (c > bk[q]) ? bk[q] : c;   // v_min_u32
        bk[q] = hi;
    }
}

// ---------------- fused normalize: hp -> bf16 ranking copy, hc -> fp32 + sq ------
// hpnb is PRE-SWIZZLED: 16B chunk q of row r stored at chunk q^(r&7). Monotone
// global_load_lds staging in k_simtop then lands the XOR-swizzled LDS layout for
// free -> conflict-free fragment ds_read_b128 (r10).
__global__ __launch_bounds__(256) void k_norm(const float* __restrict__ hp,
                                              const float* __restrict__ hc,
                                              unsigned short* __restrict__ hpnb,
                                              float* __restrict__ hcn,
                                              float* __restrict__ sqout,
                                              float* __restrict__ out) {
    int b = blockIdx.x;
    int t = threadIdx.x;
    if (b == 0 && t == 0) out[0] = 0.0f;
    bool isP = (b < BP);
    int row = isP ? b : (b - BP);
    const float* xr = (isP ? hp : hc) + (size_t)row * D;
    float v0 = xr[t], v1 = xr[t + 256], v2 = xr[t + 512];
    float s = v0 * v0 + v1 * v1 + v2 * v2;
    #pragma unroll
    for (int off = 32; off; off >>= 1) s += __shfl_xor(s, off, 64);
    __shared__ float wsum[4];
    if ((t & 63) == 0) wsum[t >> 6] = s;
    __syncthreads();
    float tot = wsum[0] + wsum[1] + wsum[2] + wsum[3];
    float rinv = 1.0f / fmaxf(sqrtf(tot), 1e-12f);
    if (isP) {
        unsigned short* yr = hpnb + (size_t)row * D;
        int rx = (row & 7) << 3;                       // chunk swizzle (bits 3..5)
        yr[t ^ rx]         = f2bf(v0 * rinv);
        yr[(t + 256) ^ rx] = f2bf(v1 * rinv);
        yr[(t + 512) ^ rx] = f2bf(v2 * rinv);
    } else {
        float* yr = hcn + (size_t)row * D;
        yr[t] = v0 * rinv; yr[t + 256] = v1 * rinv; yr[t + 512] = v2 * rinv;
        if (t == 0) sqout[row] = tot * rinv * rinv;
    }
}

// ---------------- 256^2-tile 8-phase MFMA similarity + fused per-row top-6 -------
// r18: T3+T4+T5 port. 512 blocks x 512 threads (8 waves, 2Mx4N). BM=BN=256,
// BK=64, double-buffered LDS (tile parity = buffer index). Per phase:
// [ds_reads][stage chunk][s_barrier][lgkmcnt(0)+sched_barrier][setprio(1) 16 MFMA
// setprio(0)][counted vmcnt @P4/P8][s_barrier]. Chunk-granular prefetch with
// per-chunk deadness: B-chunks of a buffer die after its 2nd phase, A-chunks
// after its 3rd -> stage slots P3,P4(B),P5,P6(A) for next even tile; P7(B),P8(A)
// for next odd tile. vmcnt(4)@P4 / vmcnt(8)@P8: loads stay in flight ACROSS
// barriers (the m97 structure's vmcnt(0)-drain was the ~30% stall: MfmaUtil 36%).
// Last iteration stages nothing -> its P4 must drain (vmcnt(0)).
// Numerics: MFMA chain order per acc element identical to r17 (tiles ascending,
// ks0->ks1) -> bit-identical scores, same +4 bias / 7-bit col packing, same
// candv/candi layout (each block emits the two 128-col tiles 2*ci2, 2*ci2+1).
__global__ __launch_bounds__(512, 2) void k_simtop(const unsigned short* __restrict__ hp,
                                                   float* __restrict__ candv,
                                                   int* __restrict__ candi) {
    __shared__ char smem[139264];   // staging 2x64KB; epilogue sS 256x129x4 + mk 256x7x4

    const int t = threadIdx.x;
    const int l = t & 63;
    const int wid = t >> 6;
    const int l15 = l & 15, quad = l >> 4;
    const int wr = wid >> 2, wc = wid & 3;      // wave grid 2(M) x 4(N)

    // XCD super-tile swizzle: 512 blocks, xcd = b&7, 4x4-block super-tiles
    // (A+B panels 1.5+1.5 MB < 4 MB per-XCD L2). Bijective.
    int ri2, ci2;
    {
        int b = blockIdx.x;
        int super_id = (((b >> 7) & 3) << 3) | (b & 7);  // 0..31 on a 4x8 super grid
        int within = (b >> 3) & 15;                       // 0..15 (4x4 walk)
        ri2 = (super_id >> 3) * 4 + (within >> 2);        // 0..15
        ci2 = (super_id & 7) * 4 + (within & 3);          // 0..31
    }

    // per-thread staging source: row group t>>3 (64 rows/round), chunk t&7.
    // LDS dest linear: t*16 = wid*1024 + lane*16 (wave-uniform base + lane*16).
    const unsigned short* As = hp + (size_t)(ri2 * 256 + (t >> 3)) * D + (t & 7) * 8;
    const unsigned short* Bs = hp + (size_t)(ci2 * 256 + (t >> 3)) * D + (t & 7) * 8;
    char* ldsbase = smem + wid * 1024;

// chunk c: 0=A rows 0-127, 1=A rows 128-255, 2=B rows 0-127, 3=B rows 128-255.
// One chunk = 2 gload16 rounds/thread (vmcnt math: 2 loads per chunk).
#define STAGE(buf, kt, c) do {                                                        \
    const unsigned short* _s = ((c) < 2 ? As : Bs) + (size_t)(((c) & 1) * 128) * D + (kt) * 64; \
    char* _d = ldsbase + (buf) * 65536 + ((c) >= 2 ? 32768 : 0) + ((c) & 1) * 16384;  \
    gload16(_s, _d);                                                                  \
    gload16(_s + 64 * D, _d + 8192);                                                  \
} while (0)

    // fragment chunk offsets (conflict-free): original k-chunk q of row r sits
    // at LDS chunk q^(r&7); frag rows have r&7 == l15&7.
    const int x7  = l15 & 7;
    const int ch0 = (quad ^ x7) * 16;
    const int ch1 = ((quad + 4) ^ x7) * 16;
    const int aRow = (wr * 128 + l15) << 7;            // byte offset in A region
    const int bRow = 32768 + ((wc * 64 + l15) << 7);   // byte offset in B region

#define READ_AH(dst, h, bb)                                               \
    _Pragma("unroll")                                                     \
    for (int mi = 0; mi < 4; mi++) {                                      \
        const char* _p = smem + (bb) + aRow + (((h) * 64 + mi * 16) << 7);\
        dst[mi][0] = *(const bf16x8*)(_p + ch0);                          \
        dst[mi][1] = *(const bf16x8*)(_p + ch1);                          \
    }

#define READ_BH(dst, h, bb)                                               \
    _Pragma("unroll")                                                     \
    for (int ni = 0; ni < 2; ni++) {                                      \
        const char* _p = smem + (bb) + bRow + (((h) * 32 + ni * 16) << 7);\
        dst[ni][0] = *(const bf16x8*)(_p + ch0);                          \
        dst[ni][1] = *(const bf16x8*)(_p + ch1);                          \
    }

#define MFMA_Q(afr, bfr, mh, nh)                                                      \
    _Pragma("unroll")                                                                 \
    for (int mi = 0; mi < 4; mi++)                                                    \
    _Pragma("unroll")                                                                 \
    for (int ni = 0; ni < 2; ni++)                                                    \
    _Pragma("unroll")                                                                 \
    for (int ks = 0; ks < 2; ks++)                                                    \
        acc[(mh) * 4 + mi][(nh) * 2 + ni] = __builtin_amdgcn_mfma_f32_16x16x32_bf16(  \
            afr[mi][ks], bfr[ni][ks], acc[(mh) * 4 + mi][(nh) * 2 + ni], 0, 0, 0);

#define PH_TOP()  do { __builtin_amdgcn_s_barrier();                                  \
                       asm volatile("s_waitcnt lgkmcnt(0)" ::: "memory");             \
                       __builtin_amdgcn_sched_barrier(0);                             \
                       __builtin_amdgcn_s_setprio(1); } while (0)
#define PH_END()  do { __builtin_amdgcn_s_setprio(0);                                 \
                       __builtin_amdgcn_sched_barrier(0); } while (0)

    // C-init = +4.0 bias: scores positive -> raw bits unsigned-compare monotone.
    f32x4 acc[8][4];
    #pragma unroll
    for (int i = 0; i < 8; i++)
        #pragma unroll
        for (int j = 0; j < 4; j++) acc[i][j] = (f32x4){4.f, 4.f, 4.f, 4.f};

    // prologue: tile 0 -> buf0, tile 1 -> buf1 (16 loads); wait tile0 (allow tile1)
    STAGE(0, 0, 0); STAGE(0, 0, 1); STAGE(0, 0, 2); STAGE(0, 0, 3);
    STAGE(1, 1, 0); STAGE(1, 1, 1); STAGE(1, 1, 2); STAGE(1, 1, 3);
    asm volatile("s_waitcnt vmcnt(8)" ::: "memory");
    __builtin_amdgcn_s_barrier();

    bf16x8 a0[4][2], a1[4][2], b0v[2][2], b1v[2][2];

    for (int it = 0; it < NIT; ++it) {
        const int kt0 = 2 * it;
        const bool pf = (it < NIT - 1);
        // ================= tile kt0 (buf0, bytes 0) =================
        // P1: reads A-half0 + B-pair0 (12 ds_read_b128); MFMA quadrant (0,0)
        READ_AH(a0, 0, 0); READ_BH(b0v, 0, 0);
        PH_TOP(); MFMA_Q(a0, b0v, 0, 0); PH_END();
        __builtin_amdgcn_s_barrier();
        // P2: reads B-pair1 (4); MFMA (0,1). buf0 B-chunks now fully read.
        READ_BH(b1v, 1, 0);
        PH_TOP(); MFMA_Q(a0, b1v, 0, 1); PH_END();
        __builtin_amdgcn_s_barrier();
        // P3: reads A-half1 (8); stage next-even B-lo into buf0 (region dead).
        READ_AH(a1, 1, 0);
        if (pf) STAGE(0, kt0 + 2, 2);
        PH_TOP(); MFMA_Q(a1, b1v, 1, 1); PH_END();
        __builtin_amdgcn_s_barrier();
        // P4: stage B-hi; MFMA (1,0); counted vmcnt: odd tile (buf1) must have
        // landed; the 4 newest (this iter's B stages) stay in flight.
        if (pf) STAGE(0, kt0 + 2, 3);
        PH_TOP(); MFMA_Q(a1, b0v, 1, 0); PH_END();
        if (pf) { asm volatile("s_waitcnt vmcnt(4)" ::: "memory"); }
        else    { asm volatile("s_waitcnt vmcnt(0)" ::: "memory"); }
        __builtin_amdgcn_s_barrier();
        // ================= tile kt0+1 (buf1, bytes 65536) =================
        // P5: reads from buf1; stage next-even A-lo (buf0 A dead since P3).
        READ_AH(a0, 0, 65536); READ_BH(b0v, 0, 65536);
        if (pf) STAGE(0, kt0 + 2, 0);
        PH_TOP(); MFMA_Q(a0, b0v, 0, 0); PH_END();
        __builtin_amdgcn_s_barrier();
        // P6: stage A-hi.
        READ_BH(b1v, 1, 65536);
        if (pf) STAGE(0, kt0 + 2, 1);
        PH_TOP(); MFMA_Q(a0, b1v, 0, 1); PH_END();
        __builtin_amdgcn_s_barrier();
        // P7: stage next-odd B chunks into buf1 (buf1 B dead after P6).
        READ_AH(a1, 1, 65536);
        if (pf) { STAGE(1, kt0 + 3, 2); STAGE(1, kt0 + 3, 3); }
        PH_TOP(); MFMA_Q(a1, b1v, 1, 1); PH_END();
        __builtin_amdgcn_s_barrier();
        // P8: stage next-odd A chunks (buf1 A dead after P7); counted vmcnt:
        // next even tile (8 loads, P3-P6) landed; 8 newest (P7/P8) in flight.
        if (pf) { STAGE(1, kt0 + 3, 0); STAGE(1, kt0 + 3, 1); }
        PH_TOP(); MFMA_Q(a1, b0v, 1, 0); PH_END();
        asm volatile("s_waitcnt vmcnt(8)" ::: "memory");
        __builtin_amdgcn_s_barrier();
    }

#undef STAGE
#undef READ_AH
#undef READ_BH
#undef MFMA_Q
#undef PH_TOP
#undef PH_END

    // ---------------- epilogue: 2 col-half rounds (128-col tile granularity) ----
    unsigned* sS = (unsigned*)smem;                    // [256][129] packed keys
    unsigned* mk = (unsigned*)(smem + 132096);         // [256][7] partner lists
    const int myH = wc >> 1;
    const int colbase = (wc & 1) * 64;

    #pragma unroll
    for (int H = 0; H < 2; H++) {
        __syncthreads();
        if (myH == H) {
            // dumping waves (4 of 8) write ALL their frags for this col-half
            #pragma unroll
            for (int ni = 0; ni < 4; ni++) {
                int colL = colbase + ni * 16 + l15;        // 0..127 within half
                unsigned pk = (unsigned)(127 - colL);      // smaller col wins ties
                #pragma unroll
                for (int mi = 0; mi < 8; mi++) {
                    int rowb = wr * 128 + mi * 16 + quad * 4;
                    f32x4 v = acc[mi][ni];
                    #pragma unroll
                    for (int r = 0; r < 4; r++)
                        sS[(rowb + r) * 129 + colL] =
                            (__float_as_uint(v[r]) & 0xFFFFFF80u) | pk;
                }
            }
        }
        __syncthreads();
        // scan: 2 threads/row x 64 cols (stride 129 words -> conflict-free)
        unsigned bk[TOPK];
        #pragma unroll
        for (int s = 0; s < TOPK; s++) bk[s] = 0u;
        const unsigned* rowp = sS + (t & 255) * 129 + (t >> 8) * 64;
        #pragma unroll
        for (int c = 0; c < 64; c++) topk_insert_u(rowp[c], bk);
        if (t >= 256) {
            #pragma unroll
            for (int s = 0; s < TOPK; s++) mk[(t - 256) * 7 + s] = bk[s];
        }
        __syncthreads();
        if (t < 256) {
            #pragma unroll
            for (int s0 = 0; s0 < TOPK; s0++) topk_insert_u(mk[t * 7 + s0], bk);
            size_t o = ((size_t)(ri2 * 256 + t) * NT + (ci2 * 2 + H)) * TOPK;
            #pragma unroll
            for (int s = 0; s < TOPK; s++) {
                unsigned k = bk[s];
                candv[o + s] = __uint_as_float(k & 0xFFFFFF80u);   // quantized biased score
                candi[o + s] = ci2 * 256 + H * 128 + 127 - (int)(k & 127u);
            }
        }
    }
}

// ------- fused merge (wave-parallel) + sparse loss + global atomic accumulate ----
// Unchanged from r17 (candv/candi layout preserved by the r18 k_simtop).
__global__ __launch_bounds__(256) void k_mergeloss(const float* __restrict__ candv,
                                                   const int* __restrict__ candi,
                                                   const float* __restrict__ hcn,
                                                   const float* __restrict__ sq,
                                                   const int* __restrict__ labp,
                                                   float* __restrict__ out) {
    __shared__ float bsum[4];
    const int w = threadIdx.x >> 6, lane = threadIdx.x & 63;
    const int i = blockIdx.x * 4 + w;

    const float* cv = candv + ((size_t)i * NT + lane) * TOPK;
    const int*   cj = candi + ((size_t)i * NT + lane) * TOPK;
    float bv[TOPK]; int bj[TOPK];
    #pragma unroll
    for (int s = 0; s < TOPK; s++) { bv[s] = cv[s]; bj[s] = cj[s]; }

    #pragma unroll
    for (int off = 1; off < 64; off <<= 1) {
        float pv[TOPK]; int pj[TOPK];
        #pragma unroll
        for (int s = 0; s < TOPK; s++) {
            pv[s] = __shfl_xor(bv[s], off, 64);
            pj[s] = __shfl_xor(bj[s], off, 64);
        }
        bool ilow = (lane & off) == 0;
        float av[TOPK], iv[TOPK]; int aj[TOPK], ij[TOPK];
        #pragma unroll
        for (int s = 0; s < TOPK; s++) {
            av[s] = ilow ? bv[s] : pv[s];  aj[s] = ilow ? bj[s] : pj[s];
            iv[s] = ilow ? pv[s] : bv[s];  ij[s] = ilow ? pj[s] : bj[s];
        }
        #pragma unroll
        for (int s = 0; s < TOPK; s++)
            if (iv[s] > av[TOPK - 1]) topk_insert(iv[s], ij[s], av, aj);
        #pragma unroll
        for (int s = 0; s < TOPK; s++) { bv[s] = av[s]; bj[s] = aj[s]; }
    }

    // loss: ranks 1..5 (rank 0 is self — biased self-score 5.0 is still max).
    const float* hi = hcn + (size_t)i * D;
    float4 h0 = *(const float4*)(hi + lane * 4);
    float4 h1 = *(const float4*)(hi + lane * 4 + 256);
    float4 h2 = *(const float4*)(hi + lane * 4 + 512);
    float sqi = sq[i];
    int li = labp[i];
    float part = 0.f;
    float base = 0.f;
    #pragma unroll
    for (int s = 1; s <= KNB; s++) {
        int j = bj[s];
        if (j >= BC) continue;
        const float* hj = hcn + (size_t)j * D;
        float4 g0 = *(const float4*)(hj + lane * 4);
        float4 g1 = *(const float4*)(hj + lane * 4 + 256);
        float4 g2 = *(const float4*)(hj + lane * 4 + 512);
        float d = h0.x * g0.x + h0.y * g0.y + h0.z * g0.z + h0.w * g0.w
                + h1.x * g1.x + h1.y * g1.y + h1.z * g1.z + h1.w * g1.w
                + h2.x * g2.x + h2.y * g2.y + h2.z * g2.z + h2.w * g2.w;
        float e = (li == labp[j]) ? 1.0f : -1.0f;
        part += e * (-2.0f) * d;
        if (lane == 0) base += e * (sqi + sq[j]);
    }
    part += base;
    #pragma unroll
    for (int off = 32; off; off >>= 1) part += __shfl_xor(part, off, 64);
    if (lane == 0) bsum[w] = part;
    __syncthreads();
    if (threadIdx.x == 0) {
        float s = bsum[0] + bsum[1] + bsum[2] + bsum[3];
        unsafeAtomicAdd(out, 0.5f * s / ((float)BC * (float)BC));
    }
}

extern "C" void kernel_launch(void* const* d_in, const int* in_sizes, int n_in,
                              void* d_out, int out_size, void* d_ws, size_t ws_size,
                              hipStream_t stream) {
    const float* hc   = (const float*)d_in[0];  // hidden_current  (4096,768)
    const float* hp   = (const float*)d_in[1];  // hidden_previous (8192,768)
    const int*   labp = (const int*)d_in[3];    // labels_previous (8192,)
    float* out = (float*)d_out;

    // workspace layout (~38 MB)
    unsigned short* hpnb = (unsigned short*)d_ws;          // BP*D bf16 (pre-swizzled)
    float* hcn  = (float*)(hpnb + (size_t)BP * D);         // BC*D f32
    float* sq   = hcn + (size_t)BC * D;                    // BC
    float* candv = sq + BC;                                // BC*NT*TOPK
    int*   candi = (int*)(candv + (size_t)BC * NT * TOPK); // BC*NT*TOPK

    k_norm<<<dim3(BP + BC), dim3(256), 0, stream>>>(hp, hc, hpnb, hcn, sq, out);
    k_simtop<<<dim3(512), dim3(512), 0, stream>>>(hpnb, candv, candi);
    k_mergeloss<<<dim3(BC / 4), dim3(256), 0, stream>>>(candv, candi, hcn, sq, labp, out);
}